// Round 14
// baseline (485.192 us; speedup 1.0000x reference)
//
#include <hip/hip_runtime.h>
#include <hip/hip_fp16.h>

#define NN 100000
#define NE 1000000
#define FIN 64
#define FHID 32
#define NB 782                    // dst>>7 buckets
#define BNODES 128
#define NCH 256                   // edge chunks
#define CH ((NE + NCH - 1) / NCH) // 3907
#define GEMB ((NN + 31) / 32)     // 3125
#define LROW 33                   // padded LDS row stride (f32): bank = (dl*33+c)%32 varies with dl

union H8 { __half2 h2[4]; float4 f4; };
union H4 { __half2 h2[2]; float2 f2; };

// ---------------- pass A: per-chunk LDS bucket histogram; phist[k][b] chunk-major ----------------
__global__ __launch_bounds__(256) void k_bhist(const int* __restrict__ dst, int* __restrict__ phist) {
    __shared__ int lh[NB];
    for (int i = threadIdx.x; i < NB; i += 256) lh[i] = 0;
    __syncthreads();
    int k = blockIdx.x;
    int e0 = k * CH, e1 = min(e0 + CH, NE);
    for (int e = e0 + threadIdx.x; e < e1; e += 256) atomicAdd(&lh[dst[e] >> 7], 1);
    __syncthreads();
    for (int b = threadIdx.x; b < NB; b += 256) phist[(size_t)k * NB + b] = lh[b];
}

// ---------------- pass B1: per-bucket scan over 256 chunks ----------------
__global__ __launch_bounds__(256) void k_bscan(int* __restrict__ phist, int* __restrict__ btot) {
    int b = blockIdx.x;
    int k = threadIdx.x;
    int v = phist[(size_t)k * NB + b];
    int lane = k & 63, wv = k >> 6;
    int incl = v;
#pragma unroll
    for (int s = 1; s < 64; s <<= 1) {
        int t = __shfl_up(incl, s, 64);
        if (lane >= s) incl += t;
    }
    __shared__ int wt[4];
    if (lane == 63) wt[wv] = incl;
    __syncthreads();
    int add = 0;
#pragma unroll
    for (int w = 0; w < 4; ++w) add += (w < wv) ? wt[w] : 0;
    phist[(size_t)k * NB + b] = add + incl - v;
    if (k == 255) btot[b] = add + incl;
}

// ---------------- pass B2: cross-bucket scan (1 block) ----------------
__global__ __launch_bounds__(1024) void k_bbase(const int* __restrict__ btot, int* __restrict__ bbase) {
    __shared__ int s[1024];
    int b = threadIdx.x;
    int v = (b < NB) ? btot[b] : 0;
    s[b] = v;
    __syncthreads();
    for (int d = 1; d < 1024; d <<= 1) {
        int t = (b >= d) ? s[b - d] : 0;
        __syncthreads();
        s[b] += t;
        __syncthreads();
    }
    if (b < NB) bbase[b] = s[b] - v;
    if (b == 0) bbase[NB] = NE;
}

// ---------------- pass C: bucket-scatter (packed 4B) || gemm1 ----------------
__global__ __launch_bounds__(256) void k_scatter_gemm1(const int* __restrict__ ei,
                                                       const int* __restrict__ phist,
                                                       const int* __restrict__ bbase,
                                                       int* __restrict__ ebuf,
                                                       const float* __restrict__ x,
                                                       const float* __restrict__ W1,
                                                       __half* __restrict__ h1) {
    int r = blockIdx.x;
    bool issc;
    int id;
    if (r < 2 * NCH) { issc = !(r & 1); id = r >> 1; }
    else             { issc = false;    id = r - NCH; }
    if (issc) {
        __shared__ int lh[NB];
        __shared__ int lbase[NB];
        int k = id;
        for (int b = threadIdx.x; b < NB; b += 256) {
            lh[b] = 0;
            lbase[b] = bbase[b] + phist[(size_t)k * NB + b];
        }
        __syncthreads();
        int e0 = k * CH, e1 = min(e0 + CH, NE);
        for (int e = e0 + threadIdx.x; e < e1; e += 256) {
            int s = ei[e], d = ei[NE + e];
            int bb = d >> 7;
            int rr = atomicAdd(&lh[bb], 1);
            ebuf[lbase[bb] + rr] = s * BNODES + (d & 127);
        }
        return;
    }
    // gemm1: h1 = x @ W1 (fp16 out, unscaled; k_degdis scales by dis in place)
    __shared__ float Wl[FIN * FHID];
    for (int t = threadIdx.x; t < FIN * FHID / 4; t += 256)
        reinterpret_cast<float4*>(Wl)[t] = reinterpret_cast<const float4*>(W1)[t];
    __syncthreads();
    int row = id * 32 + (threadIdx.x >> 3);
    int l = threadIdx.x & 7;
    if (row >= NN) return;
    const float4* xr = reinterpret_cast<const float4*>(x + (size_t)row * FIN);
    float4 acc = make_float4(0.f, 0.f, 0.f, 0.f);
#pragma unroll
    for (int k4 = 0; k4 < FIN / 4; ++k4) {
        float4 a4 = xr[k4];
#pragma unroll
        for (int j = 0; j < 4; ++j) {
            float a = j == 0 ? a4.x : j == 1 ? a4.y : j == 2 ? a4.z : a4.w;
            const float4 wv = *reinterpret_cast<const float4*>(Wl + (k4 * 4 + j) * FHID + l * 4);
            acc.x += a * wv.x; acc.y += a * wv.y; acc.z += a * wv.z; acc.w += a * wv.w;
        }
    }
    H4 u;
    u.h2[0] = __floats2half2_rn(acc.x, acc.y);
    u.h2[1] = __floats2half2_rn(acc.z, acc.w);
    *reinterpret_cast<float2*>(h1 + (size_t)row * FHID + l * 4) = u.f2;
}

// ---------------- pass D: per-bucket degree -> dis + in-place prescale h1 *= dis ----------------
__global__ __launch_bounds__(256) void k_degdis(const int* __restrict__ ebuf, const int* __restrict__ bbase,
                                                float* __restrict__ dis, __half* __restrict__ h1) {
    __shared__ int nh[BNODES];
    __shared__ float sdis[BNODES];
    int b = blockIdx.x;
    int n0 = b * BNODES;
    int ebeg = bbase[b], eend = bbase[b + 1];
    if (threadIdx.x < BNODES) nh[threadIdx.x] = 0;
    __syncthreads();
    for (int e = ebeg + threadIdx.x; e < eend; e += 256) atomicAdd(&nh[ebuf[e] & 127], 1);
    __syncthreads();
    if (threadIdx.x < BNODES) {
        float dv = rsqrtf((float)nh[threadIdx.x] + 1.0f);
        sdis[threadIdx.x] = dv;
        int n = n0 + threadIdx.x;
        if (n < NN) dis[n] = dv;
    }
    __syncthreads();
    // scale h1 rows in place: 2 threads/row x 32B
    int r = threadIdx.x >> 1, part = threadIdx.x & 1;
    int n = n0 + r;
    if (n < NN) {
        float dv = sdis[r];
        float4* pr = reinterpret_cast<float4*>(h1 + (size_t)n * FHID + part * 16);
#pragma unroll
        for (int j = 0; j < 2; ++j) {
            float4 v4 = pr[j];
            __half2* hp = reinterpret_cast<__half2*>(&v4);
#pragma unroll
            for (int u = 0; u < 4; ++u) {
                float2 f = __half22float2(hp[u]);
                hp[u] = __floats2half2_rn(f.x * dv, f.y * dv);
            }
            pr[j] = v4;
        }
    }
}

// ---------------- edge-parallel LDS bucket aggregation (NO per-node loop, NO dep chains) ----------------
// 8 lanes/edge: coalesced 64B row fetch + 4 LDS atomicAdds per lane.
// RELU=1: out = dn*relu(dn*(agg+self) + b1)  (prescaled for next layer)
// RELU=0: out = dn*(agg+self)
template <int RELU>
__global__ __launch_bounds__(256) void k_agg(const int* __restrict__ ebuf, const int* __restrict__ bbase,
                                             const float* __restrict__ dis, const __half* __restrict__ hin,
                                             const float* __restrict__ bias, __half* __restrict__ out) {
    __shared__ float aggL[BNODES * LROW];  // 16.9 KB
    for (int i = threadIdx.x; i < BNODES * LROW; i += 256) aggL[i] = 0.f;
    __syncthreads();
    int b = blockIdx.x;
    int n0 = b * BNODES;
    int ebeg = bbase[b], eend = bbase[b + 1];
    int slot = threadIdx.x >> 3, l8 = threadIdx.x & 7;
    for (int e = ebeg + slot; e < eend; e += 32) {
        int pk = ebuf[e];                    // 8 lanes same addr -> broadcast
        int s = pk >> 7, dl = pk & 127;
        float2 v = *reinterpret_cast<const float2*>(hin + (size_t)s * FHID + l8 * 4);
        const __half2* hp = reinterpret_cast<const __half2*>(&v);
        float2 f0 = __half22float2(hp[0]);
        float2 f1 = __half22float2(hp[1]);
        float* ap = aggL + dl * LROW + l8 * 4;
        atomicAdd(ap + 0, f0.x);
        atomicAdd(ap + 1, f0.y);
        atomicAdd(ap + 2, f1.x);
        atomicAdd(ap + 3, f1.y);
    }
    __syncthreads();
    // writeout: 2 threads/row, 16 cols each
    int r = threadIdx.x >> 1, part = threadIdx.x & 1;
    int n = n0 + r;
    if (n >= NN) return;
    float dn = dis[n];
    const __half* srow = hin + (size_t)n * FHID + part * 16;
    const float* ap = aggL + r * LROW + part * 16;
    float4 sv0 = *reinterpret_cast<const float4*>(srow);
    float4 sv1 = *reinterpret_cast<const float4*>(srow + 8);
    const __half2* sp0 = reinterpret_cast<const __half2*>(&sv0);
    const __half2* sp1 = reinterpret_cast<const __half2*>(&sv1);
    H8 o0, o1;
#pragma unroll
    for (int j = 0; j < 4; ++j) {
        float2 f = __half22float2(sp0[j]);
        float v0 = ap[2 * j] + f.x;
        float v1 = ap[2 * j + 1] + f.y;
        if (RELU) {
            v0 = dn * v0 + bias[part * 16 + 2 * j];
            v1 = dn * v1 + bias[part * 16 + 2 * j + 1];
            v0 = (v0 > 0.f ? v0 : 0.f) * dn;
            v1 = (v1 > 0.f ? v1 : 0.f) * dn;
        } else { v0 *= dn; v1 *= dn; }
        o0.h2[j] = __floats2half2_rn(v0, v1);
    }
#pragma unroll
    for (int j = 0; j < 4; ++j) {
        float2 f = __half22float2(sp1[j]);
        float v0 = ap[8 + 2 * j] + f.x;
        float v1 = ap[8 + 2 * j + 1] + f.y;
        if (RELU) {
            v0 = dn * v0 + bias[part * 16 + 8 + 2 * j];
            v1 = dn * v1 + bias[part * 16 + 8 + 2 * j + 1];
            v0 = (v0 > 0.f ? v0 : 0.f) * dn;
            v1 = (v1 > 0.f ? v1 : 0.f) * dn;
        } else { v0 *= dn; v1 *= dn; }
        o1.h2[j] = __floats2half2_rn(v0, v1);
    }
    *reinterpret_cast<float4*>(out + (size_t)n * FHID + part * 16) = o0.f4;
    *reinterpret_cast<float4*>(out + (size_t)n * FHID + part * 16 + 8) = o1.f4;
}

// ---------------- final GEMM: out = agg @ W2 + b2   [NN,32]x[32,64] ----------------
__global__ __launch_bounds__(256) void k_mm2(const __half* __restrict__ agg, const float* __restrict__ W2,
                                             const float* __restrict__ b2, float* __restrict__ out) {
    __shared__ float WL[FHID * FIN];  // 8 KB
    for (int t = threadIdx.x; t < FHID * FIN / 4; t += 256)
        reinterpret_cast<float4*>(WL)[t] = reinterpret_cast<const float4*>(W2)[t];
    __syncthreads();
    int row = blockIdx.x * 32 + (threadIdx.x >> 3);
    int l = threadIdx.x & 7;
    int c0 = l * 8;
    if (row >= NN) return;
    float a[32];
    const float4* pa = reinterpret_cast<const float4*>(agg + (size_t)row * FHID);
#pragma unroll
    for (int h = 0; h < 4; ++h) {
        float4 v4 = pa[h];
        const __half2* hp = reinterpret_cast<const __half2*>(&v4);
#pragma unroll
        for (int j = 0; j < 4; ++j) {
            float2 f = __half22float2(hp[j]);
            a[h * 8 + 2 * j] = f.x;
            a[h * 8 + 2 * j + 1] = f.y;
        }
    }
    float4 acc0 = *reinterpret_cast<const float4*>(b2 + c0);
    float4 acc1 = *reinterpret_cast<const float4*>(b2 + c0 + 4);
#pragma unroll
    for (int k = 0; k < FHID; ++k) {
        float av = a[k];
        const float* wr = WL + k * FIN + c0;
        const float4 w0 = *reinterpret_cast<const float4*>(wr);
        const float4 w1 = *reinterpret_cast<const float4*>(wr + 4);
        acc0.x += av * w0.x; acc0.y += av * w0.y; acc0.z += av * w0.z; acc0.w += av * w0.w;
        acc1.x += av * w1.x; acc1.y += av * w1.y; acc1.z += av * w1.z; acc1.w += av * w1.w;
    }
    float* o = out + (size_t)row * FIN + c0;
    *reinterpret_cast<float4*>(o) = acc0;
    *reinterpret_cast<float4*>(o + 4) = acc1;
}

extern "C" void kernel_launch(void* const* d_in, const int* in_sizes, int n_in,
                              void* d_out, int out_size, void* d_ws, size_t ws_size,
                              hipStream_t stream) {
    const float* x  = (const float*)d_in[0];
    const int*   ei = (const int*)d_in[1];
    const float* W1 = (const float*)d_in[2];
    const float* b1 = (const float*)d_in[3];
    const float* W2 = (const float*)d_in[4];
    const float* b2 = (const float*)d_in[5];
    float* out = (float*)d_out;

    char* w = (char*)d_ws;
    auto align = [](size_t v) { return (v + 255) & ~(size_t)255; };
    int*    phist = (int*)w;    w += align((size_t)NCH * NB * 4);
    int*    btot  = (int*)w;    w += align((size_t)NB * 4);
    int*    bbase = (int*)w;    w += align((size_t)(NB + 1) * 4);
    int*    ebuf  = (int*)w;    w += align((size_t)NE * 4);
    float*  dis   = (float*)w;  w += align((size_t)NN * 4);
    __half* h1    = (__half*)w; w += align((size_t)NN * FHID * 2);
    __half* hbuf  = (__half*)w; w += align((size_t)NN * FHID * 2);
    __half* aggb  = (__half*)w; w += align((size_t)NN * FHID * 2);

    const int* dst = ei + NE;
    k_bhist<<<NCH, 256, 0, stream>>>(dst, phist);
    k_bscan<<<NB, 256, 0, stream>>>(phist, btot);
    k_bbase<<<1, 1024, 0, stream>>>(btot, bbase);
    k_scatter_gemm1<<<NCH + GEMB, 256, 0, stream>>>(ei, phist, bbase, ebuf, x, W1, h1);
    k_degdis<<<NB, 256, 0, stream>>>(ebuf, bbase, dis, h1);
    k_agg<1><<<NB, 256, 0, stream>>>(ebuf, bbase, dis, h1, b1, hbuf);
    k_agg<0><<<NB, 256, 0, stream>>>(ebuf, bbase, dis, hbuf, nullptr, aggb);
    k_mm2<<<GEMB, 256, 0, stream>>>(aggb, W2, b2, out);
}

// Round 15
// 93.398 us; speedup vs baseline: 5.1949x; 5.1949x over previous
//
#include <hip/hip_runtime.h>
#include <hip/hip_fp16.h>

#define NN 100000
#define NE 1000000
#define FIN 64
#define FHID 32
#define NB 782                    // dst>>7 buckets
#define BNODES 128
#define NCH 256                   // edge chunks
#define CH ((NE + NCH - 1) / NCH) // 3907
#define GEMB ((NN + 31) / 32)     // 3125

union H8 { __half2 h2[4]; float4 f4; };
union H4 { __half2 h2[2]; float2 f2; };

// ---------------- pass A: per-chunk LDS bucket histogram; phist[k][b] chunk-major ----------------
__global__ __launch_bounds__(256) void k_bhist(const int* __restrict__ dst, int* __restrict__ phist) {
    __shared__ int lh[NB];
    for (int i = threadIdx.x; i < NB; i += 256) lh[i] = 0;
    __syncthreads();
    int k = blockIdx.x;
    int e0 = k * CH, e1 = min(e0 + CH, NE);
    for (int e = e0 + threadIdx.x; e < e1; e += 256) atomicAdd(&lh[dst[e] >> 7], 1);
    __syncthreads();
    for (int b = threadIdx.x; b < NB; b += 256) phist[(size_t)k * NB + b] = lh[b];
}

// ---------------- pass B1: per-bucket scan over 256 chunks ----------------
__global__ __launch_bounds__(256) void k_bscan(int* __restrict__ phist, int* __restrict__ btot) {
    int b = blockIdx.x;
    int k = threadIdx.x;
    int v = phist[(size_t)k * NB + b];
    int lane = k & 63, wv = k >> 6;
    int incl = v;
#pragma unroll
    for (int s = 1; s < 64; s <<= 1) {
        int t = __shfl_up(incl, s, 64);
        if (lane >= s) incl += t;
    }
    __shared__ int wt[4];
    if (lane == 63) wt[wv] = incl;
    __syncthreads();
    int add = 0;
#pragma unroll
    for (int w = 0; w < 4; ++w) add += (w < wv) ? wt[w] : 0;
    phist[(size_t)k * NB + b] = add + incl - v;
    if (k == 255) btot[b] = add + incl;
}

// ---------------- pass B2: cross-bucket scan (1 block) ----------------
__global__ __launch_bounds__(1024) void k_bbase(const int* __restrict__ btot, int* __restrict__ bbase,
                                                int* __restrict__ off) {
    __shared__ int s[1024];
    int b = threadIdx.x;
    int v = (b < NB) ? btot[b] : 0;
    s[b] = v;
    __syncthreads();
    for (int d = 1; d < 1024; d <<= 1) {
        int t = (b >= d) ? s[b - d] : 0;
        __syncthreads();
        s[b] += t;
        __syncthreads();
    }
    if (b < NB) bbase[b] = s[b] - v;
    if (b == 0) { bbase[NB] = NE; off[NN] = NE; }
}

// ---------------- pass C: bucket-scatter (packed 4B) || gemm1 ----------------
__global__ __launch_bounds__(256) void k_scatter_gemm1(const int* __restrict__ ei,
                                                       const int* __restrict__ phist,
                                                       const int* __restrict__ bbase,
                                                       int* __restrict__ ebuf,
                                                       const float* __restrict__ x,
                                                       const float* __restrict__ W1,
                                                       __half* __restrict__ h1) {
    int r = blockIdx.x;
    bool issc;
    int id;
    if (r < 2 * NCH) { issc = !(r & 1); id = r >> 1; }
    else             { issc = false;    id = r - NCH; }
    if (issc) {
        __shared__ int lh[NB];
        __shared__ int lbase[NB];
        int k = id;
        for (int b = threadIdx.x; b < NB; b += 256) {
            lh[b] = 0;
            lbase[b] = bbase[b] + phist[(size_t)k * NB + b];
        }
        __syncthreads();
        int e0 = k * CH, e1 = min(e0 + CH, NE);
        for (int e = e0 + threadIdx.x; e < e1; e += 256) {
            int s = ei[e], d = ei[NE + e];
            int bb = d >> 7;
            int rr = atomicAdd(&lh[bb], 1);
            ebuf[lbase[bb] + rr] = s * BNODES + (d & 127);
        }
        return;
    }
    // gemm1: h1 = x @ W1 (fp16 out, unscaled; k_csr scales by dis in place)
    __shared__ float Wl[FIN * FHID];
    for (int t = threadIdx.x; t < FIN * FHID / 4; t += 256)
        reinterpret_cast<float4*>(Wl)[t] = reinterpret_cast<const float4*>(W1)[t];
    __syncthreads();
    int row = id * 32 + (threadIdx.x >> 3);
    int l = threadIdx.x & 7;
    if (row >= NN) return;
    const float4* xr = reinterpret_cast<const float4*>(x + (size_t)row * FIN);
    float4 acc = make_float4(0.f, 0.f, 0.f, 0.f);
#pragma unroll
    for (int k4 = 0; k4 < FIN / 4; ++k4) {
        float4 a4 = xr[k4];
#pragma unroll
        for (int j = 0; j < 4; ++j) {
            float a = j == 0 ? a4.x : j == 1 ? a4.y : j == 2 ? a4.z : a4.w;
            const float4 wv = *reinterpret_cast<const float4*>(Wl + (k4 * 4 + j) * FHID + l * 4);
            acc.x += a * wv.x; acc.y += a * wv.y; acc.z += a * wv.z; acc.w += a * wv.w;
        }
    }
    H4 u;
    u.h2[0] = __floats2half2_rn(acc.x, acc.y);
    u.h2[1] = __floats2half2_rn(acc.z, acc.w);
    *reinterpret_cast<float2*>(h1 + (size_t)row * FHID + l * 4) = u.f2;
}

// ---------------- pass D: per-bucket node CSR + off + dis + in-place scale h1 *= dis ----------------
__global__ __launch_bounds__(256) void k_csr(const int* __restrict__ ebuf, const int* __restrict__ bbase,
                                             int* __restrict__ off, float* __restrict__ dis,
                                             int* __restrict__ csr, __half* __restrict__ h1) {
    __shared__ int nh[BNODES];
    __shared__ int ofl[BNODES];
    __shared__ float sdis[BNODES];
    int b = blockIdx.x;
    int n0 = b * BNODES;
    int ebeg = bbase[b], eend = bbase[b + 1];
    int ld = threadIdx.x;
    if (ld < BNODES) nh[ld] = 0;
    __syncthreads();
    for (int e = ebeg + threadIdx.x; e < eend; e += 256) atomicAdd(&nh[ebuf[e] & 127], 1);
    __syncthreads();
    int dval = (ld < BNODES) ? nh[ld] : 0;
    if (ld < BNODES) ofl[ld] = dval;
    __syncthreads();
    for (int s = 1; s < BNODES; s <<= 1) {
        int t = 0;
        if (ld < BNODES && ld >= s) t = ofl[ld - s];
        __syncthreads();
        if (ld < BNODES) ofl[ld] += t;
        __syncthreads();
    }
    if (ld < BNODES) {
        ofl[ld] -= dval;
        float dv = rsqrtf((float)dval + 1.0f);
        sdis[ld] = dv;
        int n = n0 + ld;
        if (n < NN) {
            off[n] = ebeg + ofl[ld];
            dis[n] = dv;
        }
        nh[ld] = 0;
    }
    __syncthreads();
    for (int e = ebeg + threadIdx.x; e < eend; e += 256) {
        int v = ebuf[e];
        int ldd = v & 127;
        int r = atomicAdd(&nh[ldd], 1);
        csr[ebeg + ofl[ldd] + r] = v >> 7;
    }
    // scale h1 rows of this bucket in place: h1[n] *= dis[n]  (2 threads/row, 32B each)
    int i = ld >> 1, part = ld & 1;
    int n = n0 + i;
    if (n < NN) {
        float dv = sdis[i];
        float4* pr = reinterpret_cast<float4*>(h1 + (size_t)n * FHID + part * 16);
#pragma unroll
        for (int j = 0; j < 2; ++j) {
            float4 v4 = pr[j];
            __half2* hp = reinterpret_cast<__half2*>(&v4);
#pragma unroll
            for (int u = 0; u < 4; ++u) {
                float2 f = __half22float2(hp[u]);
                hp[u] = __floats2half2_rn(f.x * dv, f.y * dv);
            }
            pr[j] = v4;
        }
    }
}

// ---------------- gather layer1: 16 lanes/node (4 nbr x 4 col), 2-edge unroll (8 rows in flight) ----------------
// reads dis-prescaled h1; writes hbuf pre-scaled by dis[n] for layer 2.
__global__ __launch_bounds__(256) void k_gather1(const int* __restrict__ off, const int* __restrict__ csr,
                                                 const float* __restrict__ dis,
                                                 const __half* __restrict__ h, const float* __restrict__ bias,
                                                 __half* __restrict__ out) {
    int t = blockIdx.x * 256 + threadIdx.x;
    int n = t >> 4;
    int l = t & 15;
    int q = l >> 2, c = l & 3;
    float dn = dis[n];
    int beg = off[n], end = off[n + 1];
    float acc[8] = {0.f, 0.f, 0.f, 0.f, 0.f, 0.f, 0.f, 0.f};
    float accB[8] = {0.f, 0.f, 0.f, 0.f, 0.f, 0.f, 0.f, 0.f};
    int p = beg + q;
    bool vA = p < end, vB = p + 4 < end;
    int sA = vA ? csr[p] : 0;
    int sB = vB ? csr[p + 4] : 0;
    while (vB) {
        int pn = p + 8;
        int sA2 = (pn < end) ? csr[pn] : 0;
        int sB2 = (pn + 4 < end) ? csr[pn + 4] : 0;
        // both independent row loads issued before either is consumed
        float4 va = *reinterpret_cast<const float4*>(h + (size_t)sA * FHID + c * 8);
        float4 vb = *reinterpret_cast<const float4*>(h + (size_t)sB * FHID + c * 8);
        const __half2* ha = reinterpret_cast<const __half2*>(&va);
        const __half2* hb = reinterpret_cast<const __half2*>(&vb);
#pragma unroll
        for (int j = 0; j < 4; ++j) {
            float2 fa = __half22float2(ha[j]);
            float2 fb = __half22float2(hb[j]);
            acc[2 * j] += fa.x;  acc[2 * j + 1] += fa.y;
            accB[2 * j] += fb.x; accB[2 * j + 1] += fb.y;
        }
        p = pn;
        vA = pn < end; vB = pn + 4 < end;
        sA = sA2; sB = sB2;
    }
    if (vA) {
        float4 va = *reinterpret_cast<const float4*>(h + (size_t)sA * FHID + c * 8);
        const __half2* ha = reinterpret_cast<const __half2*>(&va);
#pragma unroll
        for (int j = 0; j < 4; ++j) {
            float2 fa = __half22float2(ha[j]);
            acc[2 * j] += fa.x; acc[2 * j + 1] += fa.y;
        }
    }
#pragma unroll
    for (int j = 0; j < 8; ++j) {
        acc[j] += accB[j];
        acc[j] += __shfl_xor(acc[j], 4);
        acc[j] += __shfl_xor(acc[j], 8);
    }
    if (q == 0) {
        float4 sv = *reinterpret_cast<const float4*>(h + (size_t)n * FHID + c * 8);
        const __half2* sp = reinterpret_cast<const __half2*>(&sv);
#pragma unroll
        for (int j = 0; j < 4; ++j) {
            float2 f = __half22float2(sp[j]);
            acc[2 * j] += f.x;
            acc[2 * j + 1] += f.y;
        }
        const float4 b0 = *reinterpret_cast<const float4*>(bias + c * 8);
        const float4 b1v = *reinterpret_cast<const float4*>(bias + c * 8 + 4);
        float bb[8] = {b0.x, b0.y, b0.z, b0.w, b1v.x, b1v.y, b1v.z, b1v.w};
        H8 o;
#pragma unroll
        for (int j = 0; j < 4; ++j) {
            float v0 = dn * acc[2 * j] + bb[2 * j];
            float v1 = dn * acc[2 * j + 1] + bb[2 * j + 1];
            v0 = v0 > 0.f ? v0 : 0.f;
            v1 = v1 > 0.f ? v1 : 0.f;
            o.h2[j] = __floats2half2_rn(dn * v0, dn * v1);  // pre-scale for layer 2
        }
        *reinterpret_cast<float4*>(out + (size_t)n * FHID + c * 8) = o.f4;
    }
}

// ---------------- fused: gather(hbuf, 2-edge unroll) -> LDS -> @W2 + b2 -> out ----------------
// 16 nodes/block; phase B: 4 cols/thread float4.
__global__ __launch_bounds__(256) void k_gather_mm(const int* __restrict__ off, const int* __restrict__ csr,
                                                   const float* __restrict__ dis,
                                                   const __half* __restrict__ h, const float* __restrict__ W2,
                                                   const float* __restrict__ b2, float* __restrict__ out) {
    __shared__ float WL[FHID * FIN];   // 8 KB
    __shared__ float aggL[16 * 36];
    for (int t = threadIdx.x; t < FHID * FIN / 4; t += 256)
        reinterpret_cast<float4*>(WL)[t] = reinterpret_cast<const float4*>(W2)[t];

    int i = threadIdx.x >> 4;
    int l = threadIdx.x & 15;
    int q = l >> 2, c = l & 3;
    int n = blockIdx.x * 16 + i;
    {
        float dn = dis[n];
        int beg = off[n], end = off[n + 1];
        float acc[8] = {0.f, 0.f, 0.f, 0.f, 0.f, 0.f, 0.f, 0.f};
        float accB[8] = {0.f, 0.f, 0.f, 0.f, 0.f, 0.f, 0.f, 0.f};
        int p = beg + q;
        bool vA = p < end, vB = p + 4 < end;
        int sA = vA ? csr[p] : 0;
        int sB = vB ? csr[p + 4] : 0;
        while (vB) {
            int pn = p + 8;
            int sA2 = (pn < end) ? csr[pn] : 0;
            int sB2 = (pn + 4 < end) ? csr[pn + 4] : 0;
            float4 va = *reinterpret_cast<const float4*>(h + (size_t)sA * FHID + c * 8);
            float4 vb = *reinterpret_cast<const float4*>(h + (size_t)sB * FHID + c * 8);
            const __half2* ha = reinterpret_cast<const __half2*>(&va);
            const __half2* hb = reinterpret_cast<const __half2*>(&vb);
#pragma unroll
            for (int j = 0; j < 4; ++j) {
                float2 fa = __half22float2(ha[j]);
                float2 fb = __half22float2(hb[j]);
                acc[2 * j] += fa.x;  acc[2 * j + 1] += fa.y;
                accB[2 * j] += fb.x; accB[2 * j + 1] += fb.y;
            }
            p = pn;
            vA = pn < end; vB = pn + 4 < end;
            sA = sA2; sB = sB2;
        }
        if (vA) {
            float4 va = *reinterpret_cast<const float4*>(h + (size_t)sA * FHID + c * 8);
            const __half2* ha = reinterpret_cast<const __half2*>(&va);
#pragma unroll
            for (int j = 0; j < 4; ++j) {
                float2 fa = __half22float2(ha[j]);
                acc[2 * j] += fa.x; acc[2 * j + 1] += fa.y;
            }
        }
#pragma unroll
        for (int j = 0; j < 8; ++j) {
            acc[j] += accB[j];
            acc[j] += __shfl_xor(acc[j], 4);
            acc[j] += __shfl_xor(acc[j], 8);
        }
        if (q == 0) {
            float4 sv = *reinterpret_cast<const float4*>(h + (size_t)n * FHID + c * 8);
            const __half2* sp = reinterpret_cast<const __half2*>(&sv);
            float* ar = aggL + i * 36 + c * 8;
#pragma unroll
            for (int j = 0; j < 4; ++j) {
                float2 f = __half22float2(sp[j]);
                ar[2 * j] = dn * (acc[2 * j] + f.x);
                ar[2 * j + 1] = dn * (acc[2 * j + 1] + f.y);
            }
        }
    }
    __syncthreads();

    // phase B: out[r] = aggL[r] @ W2 + b2   (16 rows x 64 cols, 4 cols/thread)
    int r = threadIdx.x >> 4;
    int n2 = blockIdx.x * 16 + r;
    int c0 = (threadIdx.x & 15) * 4;
    float4 a0 = *reinterpret_cast<const float4*>(b2 + c0);
    const float* ag = aggL + r * 36;
#pragma unroll
    for (int k = 0; k < FHID; ++k) {
        float a = ag[k];
        const float4 wv = *reinterpret_cast<const float4*>(WL + k * FIN + c0);
        a0.x += a * wv.x; a0.y += a * wv.y; a0.z += a * wv.z; a0.w += a * wv.w;
    }
    *reinterpret_cast<float4*>(out + (size_t)n2 * FIN + c0) = a0;
}

extern "C" void kernel_launch(void* const* d_in, const int* in_sizes, int n_in,
                              void* d_out, int out_size, void* d_ws, size_t ws_size,
                              hipStream_t stream) {
    const float* x  = (const float*)d_in[0];
    const int*   ei = (const int*)d_in[1];
    const float* W1 = (const float*)d_in[2];
    const float* b1 = (const float*)d_in[3];
    const float* W2 = (const float*)d_in[4];
    const float* b2 = (const float*)d_in[5];
    float* out = (float*)d_out;

    char* w = (char*)d_ws;
    auto align = [](size_t v) { return (v + 255) & ~(size_t)255; };
    int*    phist = (int*)w;    w += align((size_t)NCH * NB * 4);
    int*    btot  = (int*)w;    w += align((size_t)NB * 4);
    int*    bbase = (int*)w;    w += align((size_t)(NB + 1) * 4);
    int*    ebuf  = (int*)w;    w += align((size_t)NE * 4);
    int*    off   = (int*)w;    w += align((size_t)(NN + 1) * 4);
    float*  dis   = (float*)w;  w += align((size_t)NN * 4);
    int*    csr   = (int*)w;    w += align((size_t)NE * 4);
    __half* h1    = (__half*)w; w += align((size_t)NN * FHID * 2);
    __half* hbuf  = (__half*)w; w += align((size_t)NN * FHID * 2);

    const int* dst = ei + NE;
    k_bhist<<<NCH, 256, 0, stream>>>(dst, phist);
    k_bscan<<<NB, 256, 0, stream>>>(phist, btot);
    k_bbase<<<1, 1024, 0, stream>>>(btot, bbase, off);
    k_scatter_gemm1<<<NCH + GEMB, 256, 0, stream>>>(ei, phist, bbase, ebuf, x, W1, h1);
    k_csr<<<NB, 256, 0, stream>>>(ebuf, bbase, off, dis, csr, h1);
    k_gather1<<<(NN * 16) / 256, 256, 0, stream>>>(off, csr, dis, h1, b1, hbuf);
    k_gather_mm<<<NN / 16, 256, 0, stream>>>(off, csr, dis, hbuf, W2, b2, out);
}